// Round 8
// baseline (133.096 us; speedup 1.0000x reference)
//
#include <hip/hip_runtime.h>
#include <hip/hip_bf16.h>

#define NB 4
#define NH 12
#define SEQ 4096
#define DIM 64
#define LOG2E 1.4426950408889634f

typedef __attribute__((ext_vector_type(8))) short short8;
typedef __attribute__((ext_vector_type(4))) float f32x4;
typedef __attribute__((ext_vector_type(2))) unsigned int u32x2;

static __device__ __forceinline__ unsigned int pk2(float a, float b) {
    float2 t; t.x = a; t.y = b;
    union { __hip_bfloat162 h; unsigned int u; } x;
    x.h = __float22bfloat162_rn(t);
    return x.u;
}
static __device__ __forceinline__ short8 mk8(unsigned int a, unsigned int b,
                                             unsigned int c, unsigned int d) {
    union { unsigned int u[4]; short8 s; } x;
    x.u[0] = a; x.u[1] = b; x.u[2] = c; x.u[3] = d;
    return x.s;
}

__global__ __launch_bounds__(512, 4)
void blk_attn(const float* __restrict__ Q, const float* __restrict__ K,
              const float* __restrict__ V, const float* __restrict__ M,
              float* __restrict__ O) {
    int bid = blockIdx.x;
    bid = (bid & 7) * 192 + (bid >> 3);   // XCD-aware bijective swizzle (1536 % 8 == 0)

    const int j  = bid & 31;
    const int bh = bid >> 5;
    const int b  = bh / NH;

    const size_t base = (size_t)bh * SEQ * DIM;
    const float* Qp = Q + base + (size_t)j * 128 * DIM;
    const float* Kp = K + base;
    const float* Vp = V + base;
    const float* Mp = M + (size_t)b * SEQ;
    float*       Op = O + base + (size_t)j * 128 * DIM;

    const int tid  = threadIdx.x;
    const int w    = tid >> 6;      // wave 0..7, owns queries [16w, 16w+16)
    const int lane = tid & 63;
    const int lo   = lane & 15;
    const int hi   = lane >> 4;

    // union span [kb0, kb0+384): regions A=[0,128) W0-only, B=[128,256) both, C=[256,384) W1-only
    const int  kb0 = (j == 0) ? 0 : (j == 31 ? SEQ - 384 : 128 * j - 128);
    const bool md  = (j != 0) && (j != 31);
    const float wt0 = (j == 31) ? 0.f : (md ? 0.5f : 1.f);
    const float wt1 = (j == 0)  ? 0.f : (md ? 0.5f : 1.f);

    // ---- LDS: 65.5 KB -> 2 blocks/CU ----
    __shared__ __align__(16) unsigned char smem[67072];
    auto Ks = (unsigned short (*)[64])(smem);            // [192][64]: K[key][d ^ 8*(key&7)]
    auto Vt = (unsigned short (*)[192])(smem + 24576);   // [64][192]: V^T[d][k ^ 8*((d^(d>>2))&7)]
    auto Pw = (unsigned int (*)[16][32])(smem + 49152);  // [8 waves][16 q][32 dw], dw ^ 4*(lo&7)
    auto Ml = (float*)(smem + 65536);                    // [384] mask

    if (tid < 96) {
        f32x4 mv = *reinterpret_cast<const f32x4*>(Mp + kb0 + 4 * tid);
        *reinterpret_cast<f32x4*>(&Ml[4 * tid]) = mv;
    }

    // ---- Q fragments, scaled by log2e/8 ----
    short8 qa[2];
    {
        const float qs = 0.125f * LOG2E;
        const float* qr = Qp + (size_t)(w * 16 + lo) * DIM + hi * 8;
        #pragma unroll
        for (int s = 0; s < 2; ++s) {
            f32x4 a = *reinterpret_cast<const f32x4*>(qr + 32 * s);
            f32x4 c = *reinterpret_cast<const f32x4*>(qr + 32 * s + 4);
            qa[s] = mk8(pk2(a[0] * qs, a[1] * qs), pk2(a[2] * qs, a[3] * qs),
                        pk2(c[0] * qs, c[1] * qs), pk2(c[2] * qs, c[3] * qs));
        }
    }

    float m = -3.0e38f, SA = 0.f, SB = 0.f, SC = 0.f;
    f32x4 acc[3][4];
    #pragma unroll
    for (int g = 0; g < 3; ++g)
        #pragma unroll
        for (int dt = 0; dt < 4; ++dt) { acc[g][dt][0]=0.f; acc[g][dt][1]=0.f; acc[g][dt][2]=0.f; acc[g][dt][3]=0.f; }

    const int c8 = lane & 7, r8 = lane >> 3;
    const int quad = lane & 3, colq = lane >> 2;
    const int kswz = 8 * (lo & 7);
    const int pswz = 4 * (lo & 7);

    #pragma unroll
    for (int p = 0; p < 2; ++p) {
        if (p) __syncthreads();   // prior phase's LDS reads complete before restage

        // ---- stage K: 192 rows, b128 conflict-free writes ----
        #pragma unroll
        for (int it = 0; it < 3; ++it) {
            const int row = 24 * w + 8 * it + r8;        // row & 7 == r8
            const float* kp = Kp + (size_t)(kb0 + 192 * p + row) * DIM + 8 * c8;
            f32x4 a = *reinterpret_cast<const f32x4*>(kp);
            f32x4 c = *reinterpret_cast<const f32x4*>(kp + 4);
            *reinterpret_cast<short8*>(&Ks[row][(8 * c8) ^ (8 * r8)]) =
                mk8(pk2(a[0], a[1]), pk2(a[2], a[3]), pk2(c[0], c[1]), pk2(c[2], c[3]));
        }
        // ---- stage V^T: 4x4 register transpose, b64 writes ----
        #pragma unroll
        for (int it = 0; it < 2; ++it) {
            const int kg = w + 8 * it;                   // wave-uniform
            if (kg < 12) {
                const int k0 = 16 * kg + 4 * quad;
                f32x4 vr[4];
                #pragma unroll
                for (int kk = 0; kk < 4; ++kk)
                    vr[kk] = *reinterpret_cast<const f32x4*>(
                        Vp + (size_t)(kb0 + 192 * p + k0 + kk) * DIM + 4 * colq);
                #pragma unroll
                for (int i = 0; i < 4; ++i) {
                    const int d  = 4 * colq + i;
                    const int gd = (d ^ (d >> 2)) & 7;
                    u32x2 o;
                    o[0] = pk2(vr[0][i], vr[1][i]);
                    o[1] = pk2(vr[2][i], vr[3][i]);
                    *reinterpret_cast<u32x2*>(&Vt[d][k0 ^ (8 * gd)]) = o;
                }
            }
        }
        __syncthreads();

        // ---- QK^T swapped: st[l] -> scores[key=16l+4hi+r][q=lo] ----
        f32x4 st[12];
        #pragma unroll
        for (int l = 0; l < 12; ++l) { st[l][0]=0.f; st[l][1]=0.f; st[l][2]=0.f; st[l][3]=0.f; }
        __builtin_amdgcn_s_setprio(1);
        #pragma unroll
        for (int s = 0; s < 2; ++s)
            #pragma unroll
            for (int l = 0; l < 12; ++l) {
                short8 kf = *reinterpret_cast<const short8*>(
                    &Ks[16 * l + lo][(32 * s + 8 * hi) ^ kswz]);
                st[l] = __builtin_amdgcn_mfma_f32_16x16x32_bf16(kf, qa[s], st[l], 0, 0, 0);
            }
        __builtin_amdgcn_s_setprio(0);

        // ---- mask ----
        #pragma unroll
        for (int l = 0; l < 12; ++l) {
            f32x4 mv = *reinterpret_cast<const f32x4*>(&Ml[192 * p + 16 * l + 4 * hi]);
            #pragma unroll
            for (int r = 0; r < 4; ++r) st[l][r] = fmaf(mv[r], LOG2E, st[l][r]);
        }

        // ---- online softmax (per q = lo, lane-local) ----
        float mx = st[0][0];
        #pragma unroll
        for (int l = 0; l < 12; ++l)
            #pragma unroll
            for (int r = 0; r < 4; ++r) mx = fmaxf(mx, st[l][r]);
        mx = fmaxf(mx, __shfl_xor(mx, 16));
        mx = fmaxf(mx, __shfl_xor(mx, 32));

        const float mn = fmaxf(m, mx);
        if (p) {
            const float f = exp2f(m - mn);   // rescale phase-0 state (per q = lo)
            SA *= f; SB *= f;                // score layout: q = lo  -> OK
            // acc is OUTPUT layout: lane holds q = 4*hi + r  -> redistribute f
            float fr[4];
            #pragma unroll
            for (int r = 0; r < 4; ++r) fr[r] = __shfl(f, 4 * hi + r);
            #pragma unroll
            for (int g = 0; g < 2; ++g)
                #pragma unroll
                for (int dt = 0; dt < 4; ++dt)
                    #pragma unroll
                    for (int r = 0; r < 4; ++r) acc[g][dt][r] *= fr[r];
        }
        m = mn;

        #pragma unroll
        for (int l = 0; l < 12; ++l)
            #pragma unroll
            for (int r = 0; r < 4; ++r) st[l][r] = exp2f(st[l][r] - m);

        // region sums: p0: tiles 0-7 -> SA, 8-11 -> SB; p1: 0-3 -> SB, 4-11 -> SC
        float s0 = 0.f, s1 = 0.f;
        #pragma unroll
        for (int l = 0; l < 12; ++l) {
            const float t = (st[l][0] + st[l][1]) + (st[l][2] + st[l][3]);
            const bool first = (p == 0) ? (l < 8) : (l < 4);
            if (first) s0 += t; else s1 += t;
        }
        if (p == 0) { SA += s0; SB += s1; } else { SB += s0; SC += s1; }

        // ---- pack P (unweighted) ----
        unsigned int pk[24];
        #pragma unroll
        for (int l = 0; l < 12; ++l) {
            pk[2 * l]     = pk2(st[l][0], st[l][1]);
            pk[2 * l + 1] = pk2(st[l][2], st[l][3]);
        }

        // ---- PV: 6 kq of 32 keys, per-wave P buffer (parity dbuf) ----
        #pragma unroll
        for (int kq = 0; kq < 6; ++kq) {
            const int pp = 16 * (kq & 1);
            u32x2 w0v, w1v;
            w0v[0] = pk[4 * kq + 0]; w0v[1] = pk[4 * kq + 1];
            w1v[0] = pk[4 * kq + 2]; w1v[1] = pk[4 * kq + 3];
            *reinterpret_cast<u32x2*>(&Pw[w][lo][(pp + 2 * hi)     ^ pswz]) = w0v;
            *reinterpret_cast<u32x2*>(&Pw[w][lo][(pp + 8 + 2 * hi) ^ pswz]) = w1v;
            short8 pf = *reinterpret_cast<const short8*>(&Pw[w][lo][(pp + 4 * hi) ^ pswz]);
            const int g = (p == 0) ? (kq < 4 ? 0 : 1) : (kq < 2 ? 1 : 2);
            __builtin_amdgcn_s_setprio(1);
            #pragma unroll
            for (int dt = 0; dt < 4; ++dt) {
                const int d  = 16 * dt + lo;
                const int gd = (d ^ (d >> 2)) & 7;
                short8 vf = *reinterpret_cast<const short8*>(
                    &Vt[d][(32 * kq + 8 * hi) ^ (8 * gd)]);
                acc[g][dt] = __builtin_amdgcn_mfma_f32_16x16x32_bf16(pf, vf, acc[g][dt], 0, 0, 0);
            }
            __builtin_amdgcn_s_setprio(0);
        }
    }

    // ---- coefficients per q=lo, redistribute to q=4hi+r, store ----
    SA += __shfl_xor(SA, 16); SA += __shfl_xor(SA, 32);
    SB += __shfl_xor(SB, 16); SB += __shfl_xor(SB, 32);
    SC += __shfl_xor(SC, 16); SC += __shfl_xor(SC, 32);
    const float b0 = wt0 / (SA + SB);
    const float b1 = wt1 / (SB + SC);
    const float bB = b0 + b1;
    float c0[4], cB[4], c1[4];
    #pragma unroll
    for (int r = 0; r < 4; ++r) {
        c0[r] = __shfl(b0, 4 * hi + r);
        cB[r] = __shfl(bB, 4 * hi + r);
        c1[r] = __shfl(b1, 4 * hi + r);
    }
    #pragma unroll
    for (int dt = 0; dt < 4; ++dt)
        #pragma unroll
        for (int r = 0; r < 4; ++r) {
            const float v = c0[r] * acc[0][dt][r] + cB[r] * acc[1][dt][r] + c1[r] * acc[2][dt][r];
            Op[(size_t)(w * 16 + 4 * hi + r) * DIM + 16 * dt + lo] = v;
        }
}

extern "C" void kernel_launch(void* const* d_in, const int* in_sizes, int n_in,
                              void* d_out, int out_size, void* d_ws, size_t ws_size,
                              hipStream_t stream) {
    const float* Q = (const float*)d_in[0];
    const float* K = (const float*)d_in[1];
    const float* V = (const float*)d_in[2];
    const float* M = (const float*)d_in[3];
    float* O = (float*)d_out;
    blk_attn<<<dim3(NB * NH * (SEQ / 128)), dim3(512), 0, stream>>>(Q, K, V, M, O);
}